// Round 7
// baseline (155.345 us; speedup 1.0000x reference)
//
#include <hip/hip_runtime.h>
#include <math.h>

typedef __attribute__((ext_vector_type(8))) short short8;
typedef __attribute__((ext_vector_type(4))) short short4v;
typedef __attribute__((ext_vector_type(4))) float f32x4;
typedef __attribute__((ext_vector_type(4))) float float4v;

__device__ __forceinline__ unsigned short f2bf(float f){   // RNE
  unsigned int u = __float_as_uint(f);
  u += 0x7FFFu + ((u >> 16) & 1u);
  return (unsigned short)(u >> 16);
}
__device__ __forceinline__ float bf2f(short s){
  return __uint_as_float(((unsigned int)(unsigned short)s) << 16);
}

typedef __attribute__((address_space(1))) const unsigned char* gas_t;
typedef __attribute__((address_space(3))) unsigned char* las_t;
__device__ __forceinline__ void async16(const void* g, void* l) {
  __builtin_amdgcn_global_load_lds((gas_t)g, (las_t)l, 16, 0, 0);
}

#define SC2 0.1803368801111204f   /* 0.125 * log2(e) */

// ---------------------------------------------------------------------------
// prep_w: Wt_qkv[n][k] = bf16(W_qkv[k][n]); Wt_out[n][k] = bf16(W_out[k][n])
// ---------------------------------------------------------------------------
__global__ __launch_bounds__(256) void prep_w(
    const float* __restrict__ Wqkv, const float* __restrict__ Wout,
    unsigned short* __restrict__ Wtq, unsigned short* __restrict__ Wto)
{
  int idx = blockIdx.x * 256 + threadIdx.x;
  if (idx < 192 * 512) {
    int n = idx >> 9, k = idx & 511;
    Wtq[idx] = f2bf(Wqkv[k * 192 + n]);
  } else {
    int i2 = idx - 192 * 512;
    int n = i2 >> 6, k = i2 & 63;
    Wto[i2] = f2bf(Wout[k * 512 + n]);
  }
}

// ---------------------------------------------------------------------------
// qkv single-pass: x[16384,512]fp32 @ Wt[192,512]bf16, x read ONCE.
// grid = 256 blocks x 64 rows; block computes all 192 output cols.
// W staged in LDS in 4 k-slices (48 KB, XOR-swizzled, async16).
// Wave w owns cols [48w, 48w+48): 4 rowtiles x 3 coltiles of accumulators.
// ---------------------------------------------------------------------------
__global__ __launch_bounds__(256) void qkv_kernel(
    const float* __restrict__ x,
    const unsigned short* __restrict__ Wt,
    unsigned short* __restrict__ qg,
    unsigned short* __restrict__ kg,
    unsigned short* __restrict__ vT)
{
  __shared__ __align__(16) unsigned short Wb[192][128];   // 48 KB
  const int lane = threadIdx.x & 63;
  const int wave = threadIdx.x >> 6;
  const int mrow = lane & 15;
  const int quad = lane >> 4;
  const int mb = blockIdx.x * 64;
  const int sw = mrow & 7;

  // staging: instr covers 4 rows x 16 chunks; lane -> row r0+(l>>4), chunk l&15
  const int lrow = lane >> 4;
  const int lch  = lane & 15;
#define STAGE_W(s)                                                            \
  { _Pragma("unroll")                                                         \
    for (int i = 0; i < 12; i++) {                                            \
      const int r0 = 4 * (wave * 12 + i);                                     \
      const int r  = r0 + lrow;                                               \
      const int cd = (lch & 8) | ((lch ^ (r & 7)) & 7);                       \
      async16(Wt + (size_t)r * 512 + (s) * 128 + cd * 8, &Wb[r0][0]);         \
    } }

  STAGE_W(0)

  f32x4 acc[4][3];
#pragma unroll
  for (int rt = 0; rt < 4; rt++)
#pragma unroll
    for (int ct = 0; ct < 3; ct++) acc[rt][ct] = (f32x4){0.f, 0.f, 0.f, 0.f};

  for (int s = 0; s < 4; s++) {
    __syncthreads();   // W slice visible
#pragma unroll
    for (int kkl = 0; kkl < 4; kkl++) {
      short8 af[4];
#pragma unroll
      for (int rt = 0; rt < 4; rt++) {
        const float* xp = x + (size_t)(mb + rt * 16 + mrow) * 512
                            + s * 128 + kkl * 32 + quad * 8;
        float4v a0 = *(const float4v*)(xp);
        float4v a1 = *(const float4v*)(xp + 4);
#pragma unroll
        for (int j = 0; j < 4; j++) {
          af[rt][j]     = (short)f2bf(a0[j]);
          af[rt][4 + j] = (short)f2bf(a1[j]);
        }
      }
      const int c   = kkl * 4 + quad;
      const int pos = (c & 8) | ((c ^ sw) & 7);
#pragma unroll
      for (int ct = 0; ct < 3; ct++) {
        short8 bf = *(const short8*)(&Wb[(wave * 3 + ct) * 16 + mrow][0] + pos * 8);
#pragma unroll
        for (int rt = 0; rt < 4; rt++)
          acc[rt][ct] = __builtin_amdgcn_mfma_f32_16x16x32_bf16(af[rt], bf, acc[rt][ct], 0, 0, 0);
      }
    }
    __syncthreads();   // reads done
    if (s < 3) STAGE_W(s + 1)
  }
#undef STAGE_W

  // epilogue staging buffer aliased onto Wb (all W reads done after last sync)
  unsigned short* cb = &Wb[0][0];   // treat as [64][200]
#pragma unroll
  for (int rt = 0; rt < 4; rt++)
#pragma unroll
    for (int ct = 0; ct < 3; ct++)
#pragma unroll
      for (int r = 0; r < 4; r++)
        cb[(rt * 16 + quad * 4 + r) * 200 + wave * 48 + ct * 16 + mrow] =
            f2bf(acc[rt][ct][r]);
  __syncthreads();

  // coalesced outputs: cols 0-63 -> q, 64-127 -> k, 128-191 -> vT (transposed)
  const int row = threadIdx.x >> 2;
  const int seg = (threadIdx.x & 3) * 16;
  {
    short8 w0 = *(const short8*)&cb[row * 200 + seg];
    short8 w1 = *(const short8*)&cb[row * 200 + seg + 8];
    unsigned short* p = qg + (size_t)(mb + row) * 64 + seg;
    *(short8*)(p) = w0;
    *(short8*)(p + 8) = w1;
  }
  {
    short8 w0 = *(const short8*)&cb[row * 200 + 64 + seg];
    short8 w1 = *(const short8*)&cb[row * 200 + 64 + seg + 8];
    unsigned short* p = kg + (size_t)(mb + row) * 64 + seg;
    *(short8*)(p) = w0;
    *(short8*)(p + 8) = w1;
  }
  {
    const int d  = threadIdx.x >> 2;
    const int s8 = (threadIdx.x & 3) * 16;
    const int bb = blockIdx.x >> 6;
    const int sb = mb & 4095;
    short8 w0, w1;
#pragma unroll
    for (int i = 0; i < 8; i++) {
      w0[i] = (short)cb[(s8 + i) * 200 + 128 + d];
      w1[i] = (short)cb[(s8 + 8 + i) * 200 + 128 + d];
    }
    unsigned short* dst = vT + (size_t)bb * (64 * 4096) + (size_t)d * 4096 + sb + s8;
    *(short8*)(dst) = w0;
    *(short8*)(dst + 8) = w1;
  }
}

// ---------------------------------------------------------------------------
// flash attention, m=0 (softmax shift-invariance; scores bounded so exp2 is
// safe). Split-K chunk=256, BN=64, O^T = V^T @ P^T.
// Block = 128 q rows (4 waves x 32 q). grid = 4 batches x 272 tasks = 1088.
// K/V double-buffered in LDS (stage j+1 BEFORE compute j; one sync/iter).
// ---------------------------------------------------------------------------
template <bool MASKED>
__device__ __forceinline__ void soft_pv(
    const f32x4* sA, const short8* vf, int kb, int qlane, int quad, int mrow,
    float& lacc, f32x4* o, unsigned short (*pb)[72])
{
  float p[16];
#pragma unroll
  for (int t = 0; t < 4; t++)
#pragma unroll
    for (int r = 0; r < 4; r++) {
      float v = sA[t][r];
      if (MASKED && (kb + t * 16 + quad * 4 + r > qlane)) v = -3.0e38f;
      p[t * 4 + r] = exp2f(v * SC2);
    }
  float ps = 0.f;
#pragma unroll
  for (int i = 0; i < 16; i++) ps += p[i];
  lacc += ps;
#pragma unroll
  for (int t = 0; t < 4; t++) {
    short4v pk;
#pragma unroll
    for (int r = 0; r < 4; r++) pk[r] = (short)f2bf(p[t * 4 + r]);
    *(short4v*)&pb[mrow][t * 16 + quad * 4] = pk;
  }
  short8 pf0 = *(const short8*)&pb[mrow][quad * 8];
  short8 pf1 = *(const short8*)&pb[mrow][32 + quad * 8];
#pragma unroll
  for (int c = 0; c < 4; c++) {
    o[c] = __builtin_amdgcn_mfma_f32_16x16x32_bf16(vf[2 * c],     pf0, o[c], 0, 0, 0);
    o[c] = __builtin_amdgcn_mfma_f32_16x16x32_bf16(vf[2 * c + 1], pf1, o[c], 0, 0, 0);
  }
}

__global__ __launch_bounds__(256) void attn_kernel(
    const unsigned short* __restrict__ qg,
    const unsigned short* __restrict__ kg,
    const unsigned short* __restrict__ vT,
    unsigned short* __restrict__ Opart,
    float* __restrict__ lpart)
{
  __shared__ __align__(16) unsigned short Kb[2][64][64];   // 16 KB
  __shared__ __align__(16) unsigned short Vb[2][64][64];   // 16 KB
  __shared__ __align__(16) unsigned short pbuf[4][16][72]; // 9.2 KB
  const int lane = threadIdx.x & 63;
  const int wave = threadIdx.x >> 6;
  const int mrow = lane & 15;
  const int quad = lane >> 4;
  const int sw   = mrow & 7;

  // task decode, heavy tasks (high qj) first; chunk = 256 keys
  int t = 271 - (blockIdx.x % 272);
  const int b = blockIdx.x / 272;
  int qj = 31, c = 0;
  for (int qq = 0; qq < 32; qq++) {
    const int ncq = (qq >> 1) + 1;     // chunks needed by 128-row block qq
    if (t < ncq) { qj = qq; c = t; break; }
    t -= ncq;
  }

  const int sq0w = qj * 128 + wave * 32;
  const int g0w  = b * 4096 + sq0w;

  short8 qf[2][2];
#pragma unroll
  for (int s = 0; s < 2; s++) {
    const unsigned short* qp = qg + (size_t)(g0w + 16 * s + mrow) * 64 + quad * 8;
    qf[s][0] = *(const short8*)(qp);
    qf[s][1] = *(const short8*)(qp + 32);
  }

  const int kstart = c << 8;
  const int qend   = qj * 128 + 128;
  const int kend   = (kstart + 256 < qend) ? (kstart + 256) : qend;
  const int nTb    = (kend - kstart) >> 6;   // both 64-aligned; 1..4

  f32x4 o[2][4];
#pragma unroll
  for (int s = 0; s < 2; s++)
#pragma unroll
    for (int ct = 0; ct < 4; ct++) o[s][ct] = (f32x4){0.f, 0.f, 0.f, 0.f};
  float lr[2] = {0.f, 0.f};

  const unsigned short* kbase = kg + (size_t)b * 4096 * 64;
  const unsigned short* vbase = vT + (size_t)b * 64 * 4096;
  const int shalf = lane >> 3;
  const int sch   = lane & 7;

#define STAGE_KV(kb, Kd, Vd)                                                  \
  {                                                                           \
    _Pragma("unroll")                                                         \
    for (int ii = 0; ii < 2; ii++) {                                          \
      const int r0 = wave * 16 + ii * 8;                                      \
      const int r  = r0 + shalf;                                              \
      const int cd = sch ^ (r & 7);                                           \
      async16(kbase + (size_t)((kb) + r) * 64 + cd * 8, (Kd) + r0 * 64);      \
      async16(vbase + (size_t)r * 4096 + (kb) + cd * 8, (Vd) + r0 * 64);      \
    }                                                                         \
  }

  STAGE_KV(kstart, &Kb[0][0][0], &Vb[0][0][0])
  __syncthreads();

  for (int j = 0; j < nTb; j++) {
    const int kb = kstart + 64 * j;
    if (j + 1 < nTb)
      STAGE_KV(kb + 64, &Kb[(j + 1) & 1][0][0], &Vb[(j + 1) & 1][0][0])
    const unsigned short* Kc = &Kb[j & 1][0][0];
    const unsigned short* Vc = &Vb[j & 1][0][0];

    short8 kf[8];
#pragma unroll
    for (int tt = 0; tt < 4; tt++) {
      const unsigned short* kr = Kc + (tt * 16 + mrow) * 64;
      kf[2 * tt]     = *(const short8*)(kr + (quad ^ sw) * 8);
      kf[2 * tt + 1] = *(const short8*)(kr + ((quad + 4) ^ sw) * 8);
    }
    f32x4 sA[2][4];
    bool act[2];
#pragma unroll
    for (int s = 0; s < 2; s++) {
      act[s] = (kb <= sq0w + 16 * s + 15);
      if (act[s]) {
#pragma unroll
        for (int tt = 0; tt < 4; tt++) {
          f32x4 z = (f32x4){0.f, 0.f, 0.f, 0.f};
          z = __builtin_amdgcn_mfma_f32_16x16x32_bf16(kf[2 * tt],     qf[s][0], z, 0, 0, 0);
          z = __builtin_amdgcn_mfma_f32_16x16x32_bf16(kf[2 * tt + 1], qf[s][1], z, 0, 0, 0);
          sA[s][tt] = z;
        }
      }
    }
    short8 vf[8];
#pragma unroll
    for (int cc = 0; cc < 4; cc++) {
      const unsigned short* vr = Vc + (cc * 16 + mrow) * 64;
      vf[2 * cc]     = *(const short8*)(vr + (quad ^ sw) * 8);
      vf[2 * cc + 1] = *(const short8*)(vr + ((quad + 4) ^ sw) * 8);
    }
#pragma unroll
    for (int s = 0; s < 2; s++) {
      if (!act[s]) continue;
      const int qlo = sq0w + 16 * s;
      if (kb + 63 <= qlo)
        soft_pv<false>(sA[s], vf, kb, qlo + mrow, quad, mrow, lr[s], o[s], pbuf[wave]);
      else
        soft_pv<true> (sA[s], vf, kb, qlo + mrow, quad, mrow, lr[s], o[s], pbuf[wave]);
    }
    __syncthreads();
  }
#undef STAGE_KV

  // epilogue: cross-quad l sum; unnormalized O^T partial (bf16) + l
#pragma unroll
  for (int s = 0; s < 2; s++) {
    float lt = lr[s];
    lt += __shfl_xor(lt, 16);
    lt += __shfl_xor(lt, 32);
    const size_t row = (size_t)c * 16384 + g0w + 16 * s + mrow;
#pragma unroll
    for (int ct = 0; ct < 4; ct++) {
      short4v ob;
#pragma unroll
      for (int r = 0; r < 4; r++) ob[r] = (short)f2bf(o[s][ct][r]);
      *(short4v*)(Opart + row * 64 + ct * 16 + quad * 4) = ob;
    }
    if (quad == 0) lpart[row] = lt;
  }
}

// ---------------------------------------------------------------------------
// combine partials (plain sum, m=0) + fused out-projection + coalesced store.
// grid = 1024 = 256 row-blocks x 4 col-chunks.
// ---------------------------------------------------------------------------
__global__ __launch_bounds__(256) void combine_kernel(
    const unsigned short* __restrict__ Opart,
    const float* __restrict__ lpart,
    const unsigned short* __restrict__ WtO,
    const float* __restrict__ bias,
    float* __restrict__ out)
{
  __shared__ __align__(16) unsigned short Wob[128][64];  // 16 KB
  __shared__ __align__(16) float obuf[4][16][132];       // 33.8 KB
  const int lane = threadIdx.x & 63;
  const int wave = threadIdx.x >> 6;
  const int mrow = lane & 15;
  const int quad = lane >> 4;
  const int rb = blockIdx.x >> 2;
  const int ch = blockIdx.x & 3;
  const int g0 = rb * 64 + wave * 16;
  const int nc = ((g0 & 4095) >> 8) + 1;   // 1..16 chunks of 256 keys

  {
    const int half = lane >> 3;
    const int chp  = lane & 7;
#pragma unroll
    for (int ii = 0; ii < 4; ii++) {
      const int r0 = wave * 32 + ii * 8;
      const int r  = r0 + half;
      const int cd = chp ^ (r & 7);
      async16(WtO + (size_t)(ch * 128 + r) * 64 + cd * 8, &Wob[r0][0]);
    }
  }

  float L = 0.f;
  f32x4 A0 = (f32x4){0,0,0,0}, A1 = A0, A2 = A0, A3 = A0;
  for (int cI = 0; cI < nc; cI++) {
    const size_t row = (size_t)cI * 16384 + g0 + mrow;
    L += lpart[row];
    const unsigned short* op = Opart + row * 64 + quad * 8;
    short8 x0 = *(const short8*)(op);
    short8 x1 = *(const short8*)(op + 32);
#pragma unroll
    for (int j = 0; j < 4; j++) {
      A0[j] += bf2f(x0[j]); A1[j] += bf2f(x0[4 + j]);
      A2[j] += bf2f(x1[j]); A3[j] += bf2f(x1[4 + j]);
    }
  }
  const float inv = 1.0f / L;
  short8 of0, of1;
#pragma unroll
  for (int i = 0; i < 4; i++) {
    of0[i]     = (short)f2bf(A0[i] * inv);
    of0[i + 4] = (short)f2bf(A1[i] * inv);
    of1[i]     = (short)f2bf(A2[i] * inv);
    of1[i + 4] = (short)f2bf(A3[i] * inv);
  }
  __syncthreads();   // Wob staged (hidden under the gather)

  const int sw = mrow & 7;
#pragma unroll
  for (int t = 0; t < 8; t++) {
    const int n = ch * 128 + t * 16 + mrow;
    const unsigned short* wr = &Wob[t * 16 + mrow][0];
    short8 w0 = *(const short8*)(wr + (quad ^ sw) * 8);
    short8 w1 = *(const short8*)(wr + ((quad + 4) ^ sw) * 8);
    f32x4 pr = (f32x4){0,0,0,0};
    pr = __builtin_amdgcn_mfma_f32_16x16x32_bf16(of0, w0, pr, 0, 0, 0);
    pr = __builtin_amdgcn_mfma_f32_16x16x32_bf16(of1, w1, pr, 0, 0, 0);
    const float bv = bias[n];
#pragma unroll
    for (int r = 0; r < 4; r++)
      obuf[wave][quad * 4 + r][t * 16 + mrow] = pr[r] + bv;
  }
  // wave-local LDS transpose -> coalesced float4 stores
#pragma unroll
  for (int j = 0; j < 4; j++) {
#pragma unroll
    for (int h = 0; h < 2; h++) {
      const int row = 4 * j + (lane >> 4);
      const int col = 4 * (lane & 15) + 64 * h;
      float4v v = *(const float4v*)&obuf[wave][row][col];
      *(float4v*)(out + (size_t)(g0 + row) * 512 + ch * 128 + col) = v;
    }
  }
}

// ---------------------------------------------------------------------------
extern "C" void kernel_launch(void* const* d_in, const int* in_sizes, int n_in,
                              void* d_out, int out_size, void* d_ws, size_t ws_size,
                              hipStream_t stream) {
  const float* x    = (const float*)d_in[0];   // [4,4096,512]
  const float* Wqkv = (const float*)d_in[1];   // [512,192]
  const float* Wout = (const float*)d_in[2];   // [64,512]
  const float* bout = (const float*)d_in[3];   // [512]
  float* out = (float*)d_out;                  // [4,4096,512] fp32

  unsigned short* q   = (unsigned short*)d_ws;       // 2 MB
  unsigned short* k   = q   + 16384 * 64;            // 2 MB
  unsigned short* vT  = k   + 16384 * 64;            // 2 MB
  unsigned short* Wtq = vT  + 4 * 64 * 4096;         // 192 KB
  unsigned short* Wto = Wtq + 192 * 512;             // 64 KB
  unsigned short* Opart = Wto + 512 * 64;            // [16][16384][64] bf16 = 33.5 MB
  float* lprt = (float*)(Opart + (size_t)16 * 16384 * 64);  // [16][16384] = 1 MB
  // total ws: ~41 MB (ws_size >= 256 MiB per R6 fill evidence)

  prep_w<<<512, 256, 0, stream>>>(Wqkv, Wout, Wtq, Wto);
  qkv_kernel<<<256, 256, 0, stream>>>(x, Wtq, q, k, vT);
  attn_kernel<<<1088, 256, 0, stream>>>(q, k, vT, Opart, lprt);
  combine_kernel<<<1024, 256, 0, stream>>>(Opart, lprt, Wto, bout, out);
}